// Round 2
// baseline (767.145 us; speedup 1.0000x reference)
//
#include <hip/hip_runtime.h>
#include <stdint.h>

#define C_DIM 1024
#define HW    4096
#define KPAD  1056
#define KIN   1049
#define NPIX  32768   // 8*64*64

typedef __bf16 bf16x8 __attribute__((ext_vector_type(8)));
typedef float  f32x4  __attribute__((ext_vector_type(4)));
typedef unsigned short u16x8 __attribute__((ext_vector_type(8)));

typedef const __attribute__((address_space(1))) void* gas_t;
typedef __attribute__((address_space(3))) void* las_t;

__device__ __forceinline__ unsigned short f2bf(float f) {
  unsigned u = __float_as_uint(f);
  unsigned r = u + 0x7FFFu + ((u >> 16) & 1u);
  return (unsigned short)(r >> 16);
}
__device__ __forceinline__ float bf2f(unsigned short b) {
  return __uint_as_float(((unsigned)b) << 16);
}

// ---------------------------------------------------------------------------
// K1: pack conv_w [1024][1049] fp32 -> wh/wl [1024][1056] bf16 (zero pad tail)
// ---------------------------------------------------------------------------
__global__ __launch_bounds__(256) void prep_w(const float* __restrict__ cw,
                                              unsigned short* __restrict__ wh,
                                              unsigned short* __restrict__ wl) {
  int o = blockIdx.x;
  for (int k = threadIdx.x; k < KPAD; k += 256) {
    float v = (k < KIN) ? cw[(size_t)o * KIN + k] : 0.0f;
    unsigned short h = f2bf(v);
    wh[(size_t)o * KPAD + k] = h;
    wl[(size_t)o * KPAD + k] = f2bf(v - bf2f(h));
  }
}

// ---------------------------------------------------------------------------
// K2: feature fp32 -> xh/xl rows (slice-local) cols 0..1023 + inv_norm (global)
//     One block = 64 pixels x all 1024 channels; LDS transpose.
// ---------------------------------------------------------------------------
__global__ __launch_bounds__(256) void pack_norm(const float* __restrict__ feat,
                                                 unsigned short* __restrict__ xh,
                                                 unsigned short* __restrict__ xl,
                                                 float* __restrict__ inv_norm,
                                                 int p_base) {
  __shared__ float tile[64][65];
  __shared__ float red[4][64];
  int t   = threadIdx.x;
  int p0l = blockIdx.x * 64;          // slice-local row base
  int p0g = p_base + p0l;             // global pixel base
  int b   = p0g >> 12;
  int hw0 = p0g & 4095;
  int pl = t & 63;   // pixel lane
  int q  = t >> 6;   // channel residue 0..3
  const float* fb = feat + (size_t)b * C_DIM * HW + hw0;
  float sumsq = 0.0f;
  for (int cc = 0; cc < 16; ++cc) {
#pragma unroll
    for (int i = 0; i < 16; ++i) {
      int cl = q + 4 * i;  // 0..63
      float v = fb[(size_t)(cc * 64 + cl) * HW + pl];
      sumsq += v * v;
      tile[cl][pl] = v;
    }
    __syncthreads();
#pragma unroll
    for (int r = 0; r < 2; ++r) {
      int id = t + r * 256;
      int pr = id >> 3;   // pixel row 0..63
      int c8 = id & 7;    // 8-element k chunk
      u16x8 hv, lv;
#pragma unroll
      for (int e = 0; e < 8; ++e) {
        float v = tile[c8 * 8 + e][pr];
        unsigned short h = f2bf(v);
        hv[e] = h;
        lv[e] = f2bf(v - bf2f(h));
      }
      size_t row = (size_t)(p0l + pr) * KPAD + cc * 64 + c8 * 8;
      *reinterpret_cast<u16x8*>(xh + row) = hv;
      *reinterpret_cast<u16x8*>(xl + row) = lv;
    }
    __syncthreads();
  }
  red[q][pl] = sumsq;
  __syncthreads();
  if (t < 64) {
    float s = red[0][t] + red[1][t] + red[2][t] + red[3][t];
    inv_norm[p0g + t] = 1.0f / fmaxf(sqrtf(s), 1e-12f);
  }
}

// ---------------------------------------------------------------------------
// K3: raw windowed correlation partials, 256-channel chunk, 4 ch per barrier.
//     part[chunk][j][pl] = sum_c f[p]*f[p+d_j]  (0 when shifted row OOB)
// ---------------------------------------------------------------------------
__global__ __launch_bounds__(256) void corr_part(const float* __restrict__ feat,
                                                 float* __restrict__ part,
                                                 int b_base, int npix_s) {
  __shared__ float tile[4][8][72];
  int t = threadIdx.x;
  int bid = blockIdx.x;
  int chunk = bid & 3;
  int ht = (bid >> 2) & 15;
  int bl = bid >> 6;               // local batch within slice
  int b  = b_base + bl;
  int h0 = ht * 4;
  int r0 = t >> 6;   // 0..3: compute row AND load row-group
  int w  = t & 63;
  // zero halo cols (0,1,66..71) for all 4 channel slots: 256 cells, 1/thread
  {
    int ch = t >> 6, r = (t >> 3) & 7, c = t & 7;
    int col = (c < 2) ? c : (64 + c);
    tile[ch][r][col] = 0.0f;
  }
  __syncthreads();
  const float* fb = feat + (size_t)b * C_DIM * HW;
  int c0 = chunk * 256;
  int h_lo = h0 - 2 + r0;
  int h_hi = h0 + 2 + r0;
  bool v_lo = (h_lo >= 0);                 // h_lo <= 63-... always <64
  bool v_hi = (h_hi < 64);                 // h_hi >= 2 always
  size_t off_lo = (size_t)(v_lo ? h_lo : 0) * 64 + w;
  size_t off_hi = (size_t)(v_hi ? h_hi : 0) * 64 + w;
  float acc[25];
#pragma unroll
  for (int j = 0; j < 25; ++j) acc[j] = 0.0f;
  for (int ci0 = 0; ci0 < 256; ci0 += 4) {
    float lo[4], hi[4];
#pragma unroll
    for (int cc = 0; cc < 4; ++cc) {
      size_t cb = (size_t)(c0 + ci0 + cc) * HW;
      lo[cc] = v_lo ? fb[cb + off_lo] : 0.0f;
      hi[cc] = v_hi ? fb[cb + off_hi] : 0.0f;
    }
    __syncthreads();   // previous iteration's reads done
#pragma unroll
    for (int cc = 0; cc < 4; ++cc) {
      tile[cc][r0][2 + w]     = lo[cc];
      tile[cc][r0 + 4][2 + w] = hi[cc];
    }
    __syncthreads();
#pragma unroll
    for (int cc = 0; cc < 4; ++cc) {
      float center = tile[cc][r0 + 2][2 + w];
#pragma unroll
      for (int dc = -2; dc <= 2; ++dc)
#pragma unroll
        for (int dr = -2; dr <= 2; ++dr)
          acc[(dc + 2) * 5 + (dr + 2)] += tile[cc][r0 + 2 + dr][2 + w + dc] * center;
    }
  }
  int pl = bl * 4096 + (h0 + r0) * 64 + w;
#pragma unroll
  for (int j = 0; j < 25; ++j)
    part[(size_t)(chunk * 25 + j) * npix_s + pl] = acc[j];
}

// ---------------------------------------------------------------------------
// K4: reduce 4 chunks, scale by inv[p]*inv[p+d], write x cols 1024..1055
//     (j>=25 writes zeros -> no poison ever read by gemm).
// ---------------------------------------------------------------------------
__global__ __launch_bounds__(256) void corr_reduce(const float* __restrict__ part,
                                                   const float* __restrict__ inv_norm,
                                                   unsigned short* __restrict__ xh,
                                                   unsigned short* __restrict__ xl,
                                                   int p_base, int npix_s) {
  int pl = blockIdx.x * 256 + threadIdx.x;  // slice-local
  int pg = p_base + pl;
  int w = pg & 63, h = (pg >> 6) & 63, b = pg >> 12;
  float inv_c = inv_norm[pg];
#pragma unroll
  for (int j = 0; j < 32; ++j) {
    float v = 0.0f;
    if (j < 25) {
      int dc = j / 5 - 2, dr = j % 5 - 2;
      int hh = h + dr, ww = w + dc;
      if (hh >= 0 && hh < 64 && ww >= 0 && ww < 64) {
        float s = part[(size_t)(0 * 25 + j) * npix_s + pl]
                + part[(size_t)(1 * 25 + j) * npix_s + pl]
                + part[(size_t)(2 * 25 + j) * npix_s + pl]
                + part[(size_t)(3 * 25 + j) * npix_s + pl];
        v = s * inv_c * inv_norm[(b << 12) + (hh << 6) + ww];
      }
    }
    unsigned short hb = f2bf(v);
    xh[(size_t)pl * KPAD + 1024 + j] = hb;
    xl[(size_t)pl * KPAD + 1024 + j] = f2bf(v - bf2f(hb));
  }
}

// ---------------------------------------------------------------------------
// K5: GEMM out[o][p] = relu(sum_k w[o][k]*x[p][k] + bias[o])
//     split-bf16 (3 MFMAs), BM=BN=128, BK=32, 4 waves, 16x16x32 MFMA,
//     global_load_lds staging w/ source-side XOR swizzle, XCD-clustered
//     block mapping (all 8 o-blocks of one x-panel on the same XCD).
// ---------------------------------------------------------------------------
__device__ __forceinline__ void stage_tile(const unsigned short* __restrict__ g,
                                           unsigned short* s, int t) {
#pragma unroll
  for (int r = 0; r < 2; ++r) {
    int idx = t + r * 256;
    int row = idx >> 2;                       // tile row 0..127
    int q = (idx & 3) ^ ((row >> 1) & 3);     // swizzled 16B chunk
    const unsigned short* gp = g + (size_t)row * KPAD + q * 8;
    unsigned short* sp = s + (t >> 6) * 512 + r * 2048;  // wave-uniform base
    __builtin_amdgcn_global_load_lds((gas_t)gp, (las_t)sp, 16, 0, 0);
  }
}

__global__ __launch_bounds__(256, 2) void gemm_kernel(
    const unsigned short* __restrict__ xh, const unsigned short* __restrict__ xl,
    const unsigned short* __restrict__ wh, const unsigned short* __restrict__ wl,
    const float* __restrict__ bias, float* __restrict__ out,
    int p_base, int np) {
  __shared__ __align__(16) unsigned short sAh[4096];
  __shared__ __align__(16) unsigned short sAl[4096];
  __shared__ __align__(16) unsigned short sBh[4096];
  __shared__ __align__(16) unsigned short sBl[4096];
  int t = threadIdx.x;
  int lane = t & 63;
  int wid = t >> 6;
  int wm = wid >> 1, wn = wid & 1;
  int l15 = lane & 15, l4 = lane >> 4;
  // XCD-clustered mapping: xcd = bid&7 (HW round-robin); within an XCD,
  // o cycles fastest so one x-panel's 8 o-blocks are co-resident on one L2.
  int bid = blockIdx.x;
  int xcd = bid & 7;
  int j = bid >> 3;                 // per-XCD sequence 0..np-1
  int o0 = (j & 7) * 128;
  int panel = xcd * (np >> 3) + (j >> 3);
  int p0l = panel * 128;            // slice-local pixel base

  f32x4 acc[4][4];
#pragma unroll
  for (int m = 0; m < 4; ++m)
#pragma unroll
    for (int n = 0; n < 4; ++n)
#pragma unroll
      for (int i = 0; i < 4; ++i) acc[m][n][i] = 0.0f;

  const unsigned short* Ah = wh + (size_t)o0 * KPAD;
  const unsigned short* Al = wl + (size_t)o0 * KPAD;
  const unsigned short* Bh = xh + (size_t)p0l * KPAD;
  const unsigned short* Bl = xl + (size_t)p0l * KPAD;

  for (int kt = 0; kt < KPAD / 32; ++kt) {
    int k0 = kt * 32;
    stage_tile(Ah + k0, sAh, t);
    stage_tile(Al + k0, sAl, t);
    stage_tile(Bh + k0, sBh, t);
    stage_tile(Bl + k0, sBl, t);
    __syncthreads();

    bf16x8 bhf[4], blf[4];
#pragma unroll
    for (int n = 0; n < 4; ++n) {
      int rr = wn * 64 + n * 16 + l15;
      int off = rr * 32 + ((l4 ^ ((rr >> 1) & 3)) * 8);
      bhf[n] = *reinterpret_cast<const bf16x8*>(&sBh[off]);
      blf[n] = *reinterpret_cast<const bf16x8*>(&sBl[off]);
    }
#pragma unroll
    for (int m = 0; m < 4; ++m) {
      int ra = wm * 64 + m * 16 + l15;
      int off = ra * 32 + ((l4 ^ ((ra >> 1) & 3)) * 8);
      bf16x8 ah = *reinterpret_cast<const bf16x8*>(&sAh[off]);
      bf16x8 al = *reinterpret_cast<const bf16x8*>(&sAl[off]);
#pragma unroll
      for (int n = 0; n < 4; ++n) {
        acc[m][n] = __builtin_amdgcn_mfma_f32_16x16x32_bf16(ah, bhf[n], acc[m][n], 0, 0, 0);
        acc[m][n] = __builtin_amdgcn_mfma_f32_16x16x32_bf16(al, bhf[n], acc[m][n], 0, 0, 0);
        acc[m][n] = __builtin_amdgcn_mfma_f32_16x16x32_bf16(ah, blf[n], acc[m][n], 0, 0, 0);
      }
    }
    __syncthreads();
  }

  // epilogue: D row=o (l4*4+reg), col=p (l15); hw-contiguous coalesced stores.
#pragma unroll
  for (int m = 0; m < 4; ++m) {
    int ob = o0 + wm * 64 + m * 16 + l4 * 4;
    float b0 = bias[ob], b1 = bias[ob + 1], b2 = bias[ob + 2], b3 = bias[ob + 3];
#pragma unroll
    for (int n = 0; n < 4; ++n) {
      int pg = p_base + p0l + wn * 64 + n * 16 + l15;
      int bb = pg >> 12, hw = pg & 4095;
      float* op = out + ((size_t)bb << 22) + hw;
      op[(size_t)(ob + 0) << 12] = fmaxf(acc[m][n][0] + b0, 0.0f);
      op[(size_t)(ob + 1) << 12] = fmaxf(acc[m][n][1] + b1, 0.0f);
      op[(size_t)(ob + 2) << 12] = fmaxf(acc[m][n][2] + b2, 0.0f);
      op[(size_t)(ob + 3) << 12] = fmaxf(acc[m][n][3] + b3, 0.0f);
    }
  }
}

// ---------------------------------------------------------------------------
extern "C" void kernel_launch(void* const* d_in, const int* in_sizes, int n_in,
                              void* d_out, int out_size, void* d_ws, size_t ws_size,
                              hipStream_t stream) {
  const float* feat = (const float*)d_in[0];
  const float* cw   = (const float*)d_in[1];
  const float* cb   = (const float*)d_in[2];
  float* out = (float*)d_out;

  // Batch-sliced pipeline; pick the largest slice that fits ws_size.
  // footprint(NB) = NB*4096*(KPAD*2*2 + 400) + w(4.33MB) + inv(128KB)
  int NB = 4;
  {
    auto need = [](int nb) -> size_t {
      size_t npix_s = (size_t)nb * 4096;
      return 2 * (npix_s * KPAD * 2)        // xh+xl
           + 2 * ((size_t)1024 * KPAD * 2)  // wh+wl
           + (size_t)NPIX * 4               // inv_norm (full)
           + (size_t)4 * 25 * npix_s * 4;   // part
    };
    if (ws_size >= need(4)) NB = 4;
    else if (ws_size >= need(2)) NB = 2;
    else NB = 1;
  }
  int S = 8 / NB;
  int npix_s = NB * 4096;

  char* ws = (char*)d_ws;
  size_t SZ_XS = (size_t)npix_s * KPAD * 2;
  size_t SZ_W  = (size_t)1024 * KPAD * 2;
  unsigned short* xh = (unsigned short*)(ws);
  unsigned short* xl = (unsigned short*)(ws + SZ_XS);
  unsigned short* wh = (unsigned short*)(ws + 2 * SZ_XS);
  unsigned short* wl = (unsigned short*)(ws + 2 * SZ_XS + SZ_W);
  float* inv_norm    = (float*)(ws + 2 * SZ_XS + 2 * SZ_W);
  float* part        = (float*)(ws + 2 * SZ_XS + 2 * SZ_W + (size_t)NPIX * 4);

  prep_w<<<1024, 256, 0, stream>>>(cw, wh, wl);
  for (int s = 0; s < S; ++s) {
    int b_base = s * NB;
    int p_base = b_base * 4096;
    pack_norm<<<NB * 64, 256, 0, stream>>>(feat, xh, xl, inv_norm, p_base);
    corr_part<<<NB * 64, 256, 0, stream>>>(feat, part, b_base, npix_s);
    corr_reduce<<<npix_s / 256, 256, 0, stream>>>(part, inv_norm, xh, xl, p_base, npix_s);
    gemm_kernel<<<8 * NB * 32, 256, 0, stream>>>(xh, xl, wh, wl, cb, out, p_base, NB * 32);
  }
}

// Round 4
// 501.620 us; speedup vs baseline: 1.5293x; 1.5293x over previous
//
#include <hip/hip_runtime.h>
#include <stdint.h>

#define C_DIM 1024
#define HW    4096
#define KPAD  1056
#define KIN   1049
#define NPIX  32768   // 8*64*64

typedef __bf16 bf16x8 __attribute__((ext_vector_type(8)));
typedef float  f32x4  __attribute__((ext_vector_type(4)));
typedef unsigned short u16x8 __attribute__((ext_vector_type(8)));

typedef const __attribute__((address_space(1))) void* gas_t;
typedef __attribute__((address_space(3))) void* las_t;

__device__ __forceinline__ unsigned short f2bf(float f) {
  unsigned u = __float_as_uint(f);
  unsigned r = u + 0x7FFFu + ((u >> 16) & 1u);
  return (unsigned short)(r >> 16);
}

// ---------------------------------------------------------------------------
// K1: pack conv_w [1024][1049] fp32 -> wb [1024][1056] bf16 (zero pad tail)
// ---------------------------------------------------------------------------
__global__ __launch_bounds__(256) void prep_w(const float* __restrict__ cw,
                                              unsigned short* __restrict__ wb) {
  int o = blockIdx.x;
  for (int k = threadIdx.x; k < KPAD; k += 256) {
    float v = (k < KIN) ? cw[(size_t)o * KIN + k] : 0.0f;
    wb[(size_t)o * KPAD + k] = f2bf(v);
  }
}

// ---------------------------------------------------------------------------
// K2: feature fp32 -> xb rows (slice-local) cols 0..1023 + inv_norm (global)
//     One block = 64 pixels x all 1024 channels; LDS transpose.
// ---------------------------------------------------------------------------
__global__ __launch_bounds__(256) void pack_norm(const float* __restrict__ feat,
                                                 unsigned short* __restrict__ xb,
                                                 float* __restrict__ inv_norm,
                                                 int p_base) {
  __shared__ float tile[64][65];
  __shared__ float red[4][64];
  int t   = threadIdx.x;
  int p0l = blockIdx.x * 64;          // slice-local row base
  int p0g = p_base + p0l;             // global pixel base
  int b   = p0g >> 12;
  int hw0 = p0g & 4095;
  int pl = t & 63;   // pixel lane
  int q  = t >> 6;   // channel residue 0..3
  const float* fb = feat + (size_t)b * C_DIM * HW + hw0;
  float sumsq = 0.0f;
  for (int cc = 0; cc < 16; ++cc) {
#pragma unroll
    for (int i = 0; i < 16; ++i) {
      int cl = q + 4 * i;  // 0..63
      float v = fb[(size_t)(cc * 64 + cl) * HW + pl];
      sumsq += v * v;
      tile[cl][pl] = v;
    }
    __syncthreads();
#pragma unroll
    for (int r = 0; r < 2; ++r) {
      int id = t + r * 256;
      int pr = id >> 3;   // pixel row 0..63
      int c8 = id & 7;    // 8-element k chunk
      u16x8 hv;
#pragma unroll
      for (int e = 0; e < 8; ++e) hv[e] = f2bf(tile[c8 * 8 + e][pr]);
      size_t row = (size_t)(p0l + pr) * KPAD + cc * 64 + c8 * 8;
      *reinterpret_cast<u16x8*>(xb + row) = hv;
    }
    __syncthreads();
  }
  red[q][pl] = sumsq;
  __syncthreads();
  if (t < 64) {
    float s = red[0][t] + red[1][t] + red[2][t] + red[3][t];
    inv_norm[p0g + t] = 1.0f / fmaxf(sqrtf(s), 1e-12f);
  }
}

// ---------------------------------------------------------------------------
// K3: raw windowed correlation partials, 256-channel chunk, 4 ch per barrier.
//     part[chunk][j][pl] = sum_c f[p]*f[p+d_j]  (0 when shifted row OOB)
//     5x5 window loaded into regs with row-adjacent dword reads (ds_read2).
// ---------------------------------------------------------------------------
__global__ __launch_bounds__(256) void corr_part(const float* __restrict__ feat,
                                                 float* __restrict__ part,
                                                 int b_base, int npix_s) {
  __shared__ float tile[4][8][72];
  int t = threadIdx.x;
  int bid = blockIdx.x;
  int chunk = bid & 3;
  int ht = (bid >> 2) & 15;
  int bl = bid >> 6;               // local batch within slice
  int b  = b_base + bl;
  int h0 = ht * 4;
  int r0 = t >> 6;   // 0..3: compute row AND load row-group
  int w  = t & 63;
  // zero halo cols (0,1,66..71) for all 4 channel slots: 256 cells, 1/thread
  {
    int ch = t >> 6, r = (t >> 3) & 7, c = t & 7;
    int col = (c < 2) ? c : (64 + c);
    tile[ch][r][col] = 0.0f;
  }
  __syncthreads();
  const float* fb = feat + (size_t)b * C_DIM * HW;
  int c0 = chunk * 256;
  int h_lo = h0 - 2 + r0;
  int h_hi = h0 + 2 + r0;
  bool v_lo = (h_lo >= 0);
  bool v_hi = (h_hi < 64);
  size_t off_lo = (size_t)(v_lo ? h_lo : 0) * 64 + w;
  size_t off_hi = (size_t)(v_hi ? h_hi : 0) * 64 + w;
  float acc[25];
#pragma unroll
  for (int j = 0; j < 25; ++j) acc[j] = 0.0f;
  for (int ci0 = 0; ci0 < 256; ci0 += 4) {
    float lo[4], hi[4];
#pragma unroll
    for (int cc = 0; cc < 4; ++cc) {
      size_t cb = (size_t)(c0 + ci0 + cc) * HW;
      lo[cc] = v_lo ? fb[cb + off_lo] : 0.0f;
      hi[cc] = v_hi ? fb[cb + off_hi] : 0.0f;
    }
    __syncthreads();   // previous iteration's reads done
#pragma unroll
    for (int cc = 0; cc < 4; ++cc) {
      tile[cc][r0][2 + w]     = lo[cc];
      tile[cc][r0 + 4][2 + w] = hi[cc];
    }
    __syncthreads();
#pragma unroll
    for (int cc = 0; cc < 4; ++cc) {
      // rv[dr5][dc5] = tile[cc][r0+dr5][w+dc5]; adjacent dc5 -> ds_read2
      float rv[5][5];
#pragma unroll
      for (int dr5 = 0; dr5 < 5; ++dr5) {
        const float* rp = &tile[cc][r0 + dr5][w];
#pragma unroll
        for (int dc5 = 0; dc5 < 5; ++dc5) rv[dr5][dc5] = rp[dc5];
      }
      float center = rv[2][2];
#pragma unroll
      for (int dc5 = 0; dc5 < 5; ++dc5)
#pragma unroll
        for (int dr5 = 0; dr5 < 5; ++dr5)
          acc[dc5 * 5 + dr5] += rv[dr5][dc5] * center;
    }
  }
  int pl = bl * 4096 + (h0 + r0) * 64 + w;
#pragma unroll
  for (int j = 0; j < 25; ++j)
    part[(size_t)(chunk * 25 + j) * npix_s + pl] = acc[j];
}

// ---------------------------------------------------------------------------
// K4: reduce 4 chunks, scale by inv[p]*inv[p+d], write x cols 1024..1055
//     as 4 vectorized u16x8 stores (j>=25 zeros -> no poison read by gemm).
// ---------------------------------------------------------------------------
__global__ __launch_bounds__(256) void corr_reduce(const float* __restrict__ part,
                                                   const float* __restrict__ inv_norm,
                                                   unsigned short* __restrict__ xb,
                                                   int p_base, int npix_s) {
  int pl = blockIdx.x * 256 + threadIdx.x;  // slice-local
  int pg = p_base + pl;
  int w = pg & 63, h = (pg >> 6) & 63, b = pg >> 12;
  float inv_c = inv_norm[pg];
  float vals[32];
#pragma unroll
  for (int j = 0; j < 32; ++j) {
    float v = 0.0f;
    if (j < 25) {
      int dc = j / 5 - 2, dr = j % 5 - 2;
      int hh = h + dr, ww = w + dc;
      if (hh >= 0 && hh < 64 && ww >= 0 && ww < 64) {
        float s = part[(size_t)(0 * 25 + j) * npix_s + pl]
                + part[(size_t)(1 * 25 + j) * npix_s + pl]
                + part[(size_t)(2 * 25 + j) * npix_s + pl]
                + part[(size_t)(3 * 25 + j) * npix_s + pl];
        v = s * inv_c * inv_norm[(b << 12) + (hh << 6) + ww];
      }
    }
    vals[j] = v;
  }
  unsigned short* xp = xb + (size_t)pl * KPAD + 1024;
#pragma unroll
  for (int g = 0; g < 4; ++g) {
    u16x8 pk;
#pragma unroll
    for (int e = 0; e < 8; ++e) pk[e] = f2bf(vals[g * 8 + e]);
    *reinterpret_cast<u16x8*>(xp + g * 8) = pk;
  }
}

// ---------------------------------------------------------------------------
// K5: GEMM out[o][p] = relu(sum_k w[o][k]*x[p][k] + bias[o])  — single bf16.
//     BM=BN=128, BK=32, 4 waves, 16x16x32 MFMA, global_load_lds staging w/
//     source-side XOR swizzle, XCD-clustered block mapping.
// ---------------------------------------------------------------------------
__device__ __forceinline__ void stage_tile(const unsigned short* __restrict__ g,
                                           unsigned short* s, int t) {
#pragma unroll
  for (int r = 0; r < 2; ++r) {
    int idx = t + r * 256;
    int row = idx >> 2;                       // tile row 0..127
    int q = (idx & 3) ^ ((row >> 1) & 3);     // swizzled 16B chunk
    const unsigned short* gp = g + (size_t)row * KPAD + q * 8;
    unsigned short* sp = s + (t >> 6) * 512 + r * 2048;  // wave-uniform base
    __builtin_amdgcn_global_load_lds((gas_t)gp, (las_t)sp, 16, 0, 0);
  }
}

__global__ __launch_bounds__(256, 2) void gemm_kernel(
    const unsigned short* __restrict__ xb, const unsigned short* __restrict__ wb,
    const float* __restrict__ bias, float* __restrict__ out,
    int p_base, int np) {
  __shared__ __align__(16) unsigned short sA[4096];
  __shared__ __align__(16) unsigned short sB[4096];
  int t = threadIdx.x;
  int lane = t & 63;
  int wid = t >> 6;
  int wm = wid >> 1, wn = wid & 1;
  int l15 = lane & 15, l4 = lane >> 4;
  int bid = blockIdx.x;
  int xcd = bid & 7;
  int j = bid >> 3;                 // per-XCD sequence 0..np-1
  int o0 = (j & 7) * 128;
  int panel = xcd * (np >> 3) + (j >> 3);
  int p0l = panel * 128;            // slice-local pixel base

  f32x4 acc[4][4];
#pragma unroll
  for (int m = 0; m < 4; ++m)
#pragma unroll
    for (int n = 0; n < 4; ++n)
#pragma unroll
      for (int i = 0; i < 4; ++i) acc[m][n][i] = 0.0f;

  const unsigned short* A = wb + (size_t)o0 * KPAD;
  const unsigned short* B = xb + (size_t)p0l * KPAD;

  for (int kt = 0; kt < KPAD / 32; ++kt) {
    int k0 = kt * 32;
    stage_tile(A + k0, sA, t);
    stage_tile(B + k0, sB, t);
    __syncthreads();

    bf16x8 bf[4];
#pragma unroll
    for (int n = 0; n < 4; ++n) {
      int rr = wn * 64 + n * 16 + l15;
      int off = rr * 32 + ((l4 ^ ((rr >> 1) & 3)) * 8);
      bf[n] = *reinterpret_cast<const bf16x8*>(&sB[off]);
    }
#pragma unroll
    for (int m = 0; m < 4; ++m) {
      int ra = wm * 64 + m * 16 + l15;
      int off = ra * 32 + ((l4 ^ ((ra >> 1) & 3)) * 8);
      bf16x8 af = *reinterpret_cast<const bf16x8*>(&sA[off]);
#pragma unroll
      for (int n = 0; n < 4; ++n)
        acc[m][n] = __builtin_amdgcn_mfma_f32_16x16x32_bf16(af, bf[n], acc[m][n], 0, 0, 0);
    }
    __syncthreads();
  }

  // epilogue: D row=o (l4*4+reg), col=p (l15); hw-contiguous coalesced stores.
#pragma unroll
  for (int m = 0; m < 4; ++m) {
    int ob = o0 + wm * 64 + m * 16 + l4 * 4;
    float b0 = bias[ob], b1 = bias[ob + 1], b2 = bias[ob + 2], b3 = bias[ob + 3];
#pragma unroll
    for (int n = 0; n < 4; ++n) {
      int pg = p_base + p0l + wn * 64 + n * 16 + l15;
      int bb = pg >> 12, hw = pg & 4095;
      float* op = out + ((size_t)bb << 22) + hw;
      op[(size_t)(ob + 0) << 12] = fmaxf(acc[m][n][0] + b0, 0.0f);
      op[(size_t)(ob + 1) << 12] = fmaxf(acc[m][n][1] + b1, 0.0f);
      op[(size_t)(ob + 2) << 12] = fmaxf(acc[m][n][2] + b2, 0.0f);
      op[(size_t)(ob + 3) << 12] = fmaxf(acc[m][n][3] + b3, 0.0f);
    }
  }
}

// ---------------------------------------------------------------------------
extern "C" void kernel_launch(void* const* d_in, const int* in_sizes, int n_in,
                              void* d_out, int out_size, void* d_ws, size_t ws_size,
                              hipStream_t stream) {
  const float* feat = (const float*)d_in[0];
  const float* cw   = (const float*)d_in[1];
  const float* cb   = (const float*)d_in[2];
  float* out = (float*)d_out;

  // Fixed NB=4 two-slice pipeline; ws footprint ~50MB (round-2 proved >=76.5MB).
  const int NB = 4;
  const int S = 8 / NB;
  const int npix_s = NB * 4096;

  char* ws = (char*)d_ws;
  size_t SZ_XS = (size_t)npix_s * KPAD * 2;   // 34.6 MB
  size_t SZ_W  = (size_t)1024 * KPAD * 2;     //  2.16 MB
  unsigned short* xb = (unsigned short*)(ws);
  unsigned short* wb = (unsigned short*)(ws + SZ_XS);
  float* inv_norm    = (float*)(ws + SZ_XS + SZ_W);
  float* part        = (float*)(ws + SZ_XS + SZ_W + (size_t)NPIX * 4);

  prep_w<<<1024, 256, 0, stream>>>(cw, wb);
  for (int s = 0; s < S; ++s) {
    int b_base = s * NB;
    int p_base = b_base * 4096;
    pack_norm<<<NB * 64, 256, 0, stream>>>(feat, xb, inv_norm, p_base);
    corr_part<<<NB * 64, 256, 0, stream>>>(feat, part, b_base, npix_s);
    corr_reduce<<<npix_s / 256, 256, 0, stream>>>(part, inv_norm, xb, p_base, npix_s);
    gemm_kernel<<<8 * NB * 32, 256, 0, stream>>>(xb, wb, cb, out, p_base, NB * 32);
  }
}

// Round 5
// 451.781 us; speedup vs baseline: 1.6980x; 1.1103x over previous
//
#include <hip/hip_runtime.h>
#include <stdint.h>

#define C_DIM 1024
#define HW    4096
#define KPAD  1056
#define KIN   1049
#define NPIX  32768   // 8*64*64

typedef __bf16 bf16x8 __attribute__((ext_vector_type(8)));
typedef float  f32x4  __attribute__((ext_vector_type(4)));
typedef unsigned short u16x8 __attribute__((ext_vector_type(8)));

typedef const __attribute__((address_space(1))) void* gas_t;
typedef __attribute__((address_space(3))) void* las_t;

__device__ __forceinline__ unsigned short f2bf(float f) {
  unsigned u = __float_as_uint(f);
  unsigned r = u + 0x7FFFu + ((u >> 16) & 1u);
  return (unsigned short)(r >> 16);
}

// ---------------------------------------------------------------------------
// K1: pack conv_w [1024][1049] fp32 -> wb [1024][1056] bf16 (zero pad tail)
// ---------------------------------------------------------------------------
__global__ __launch_bounds__(256) void prep_w(const float* __restrict__ cw,
                                              unsigned short* __restrict__ wb) {
  int o = blockIdx.x;
  for (int k = threadIdx.x; k < KPAD; k += 256) {
    float v = (k < KIN) ? cw[(size_t)o * KIN + k] : 0.0f;
    wb[(size_t)o * KPAD + k] = f2bf(v);
  }
}

// ---------------------------------------------------------------------------
// K2: feature fp32 -> xb rows cols 0..1023 + inv_norm
//     One block = 64 pixels x all 1024 channels; LDS transpose.
// ---------------------------------------------------------------------------
__global__ __launch_bounds__(256) void pack_norm(const float* __restrict__ feat,
                                                 unsigned short* __restrict__ xb,
                                                 float* __restrict__ inv_norm,
                                                 int p_base) {
  __shared__ float tile[64][65];
  __shared__ float red[4][64];
  int t   = threadIdx.x;
  int p0l = blockIdx.x * 64;          // slice-local row base
  int p0g = p_base + p0l;             // global pixel base
  int b   = p0g >> 12;
  int hw0 = p0g & 4095;
  int pl = t & 63;   // pixel lane
  int q  = t >> 6;   // channel residue 0..3
  const float* fb = feat + (size_t)b * C_DIM * HW + hw0;
  float sumsq = 0.0f;
  for (int cc = 0; cc < 16; ++cc) {
#pragma unroll
    for (int i = 0; i < 16; ++i) {
      int cl = q + 4 * i;  // 0..63
      float v = fb[(size_t)(cc * 64 + cl) * HW + pl];
      sumsq += v * v;
      tile[cl][pl] = v;
    }
    __syncthreads();
#pragma unroll
    for (int r = 0; r < 2; ++r) {
      int id = t + r * 256;
      int pr = id >> 3;   // pixel row 0..63
      int c8 = id & 7;    // 8-element k chunk
      u16x8 hv;
#pragma unroll
      for (int e = 0; e < 8; ++e) hv[e] = f2bf(tile[c8 * 8 + e][pr]);
      size_t row = (size_t)(p0l + pr) * KPAD + cc * 64 + c8 * 8;
      *reinterpret_cast<u16x8*>(xb + row) = hv;
    }
    __syncthreads();
  }
  red[q][pl] = sumsq;
  __syncthreads();
  if (t < 64) {
    float s = red[0][t] + red[1][t] + red[2][t] + red[3][t];
    inv_norm[p0g + t] = 1.0f / fmaxf(sqrtf(s), 1e-12f);
  }
}

// ---------------------------------------------------------------------------
// K3: raw windowed correlation partials, 256-channel chunk, 4 ch per barrier.
//     part[chunk][j][pl] = sum_c f[p]*f[p+d_j]  (0 when shifted row OOB)
//     5x5 window loaded into regs with row-adjacent dword reads (ds_read2).
// ---------------------------------------------------------------------------
__global__ __launch_bounds__(256) void corr_part(const float* __restrict__ feat,
                                                 float* __restrict__ part,
                                                 int b_base, int npix_s) {
  __shared__ float tile[4][8][72];
  int t = threadIdx.x;
  int bid = blockIdx.x;
  int chunk = bid & 3;
  int ht = (bid >> 2) & 15;
  int bl = bid >> 6;               // local batch within slice
  int b  = b_base + bl;
  int h0 = ht * 4;
  int r0 = t >> 6;   // 0..3: compute row AND load row-group
  int w  = t & 63;
  // zero halo cols (0,1,66..71) for all 4 channel slots: 256 cells, 1/thread
  {
    int ch = t >> 6, r = (t >> 3) & 7, c = t & 7;
    int col = (c < 2) ? c : (64 + c);
    tile[ch][r][col] = 0.0f;
  }
  __syncthreads();
  const float* fb = feat + (size_t)b * C_DIM * HW;
  int c0 = chunk * 256;
  int h_lo = h0 - 2 + r0;
  int h_hi = h0 + 2 + r0;
  bool v_lo = (h_lo >= 0);
  bool v_hi = (h_hi < 64);
  size_t off_lo = (size_t)(v_lo ? h_lo : 0) * 64 + w;
  size_t off_hi = (size_t)(v_hi ? h_hi : 0) * 64 + w;
  float acc[25];
#pragma unroll
  for (int j = 0; j < 25; ++j) acc[j] = 0.0f;
  for (int ci0 = 0; ci0 < 256; ci0 += 4) {
    float lo[4], hi[4];
#pragma unroll
    for (int cc = 0; cc < 4; ++cc) {
      size_t cb = (size_t)(c0 + ci0 + cc) * HW;
      lo[cc] = v_lo ? fb[cb + off_lo] : 0.0f;
      hi[cc] = v_hi ? fb[cb + off_hi] : 0.0f;
    }
    __syncthreads();   // previous iteration's reads done
#pragma unroll
    for (int cc = 0; cc < 4; ++cc) {
      tile[cc][r0][2 + w]     = lo[cc];
      tile[cc][r0 + 4][2 + w] = hi[cc];
    }
    __syncthreads();
#pragma unroll
    for (int cc = 0; cc < 4; ++cc) {
      // rv[dr5][dc5] = tile[cc][r0+dr5][w+dc5]; adjacent dc5 -> ds_read2
      float rv[5][5];
#pragma unroll
      for (int dr5 = 0; dr5 < 5; ++dr5) {
        const float* rp = &tile[cc][r0 + dr5][w];
#pragma unroll
        for (int dc5 = 0; dc5 < 5; ++dc5) rv[dr5][dc5] = rp[dc5];
      }
      float center = rv[2][2];
#pragma unroll
      for (int dc5 = 0; dc5 < 5; ++dc5)
#pragma unroll
        for (int dr5 = 0; dr5 < 5; ++dr5)
          acc[dc5 * 5 + dr5] += rv[dr5][dc5] * center;
    }
  }
  int pl = bl * 4096 + (h0 + r0) * 64 + w;
#pragma unroll
  for (int j = 0; j < 25; ++j)
    part[(size_t)(chunk * 25 + j) * npix_s + pl] = acc[j];
}

// ---------------------------------------------------------------------------
// K4: reduce 4 chunks, scale by inv[p]*inv[p+d], write x cols 1024..1055
//     as 4 vectorized u16x8 stores (j>=25 zeros -> no poison read by gemm).
// ---------------------------------------------------------------------------
__global__ __launch_bounds__(256) void corr_reduce(const float* __restrict__ part,
                                                   const float* __restrict__ inv_norm,
                                                   unsigned short* __restrict__ xb,
                                                   int p_base, int npix_s) {
  int pl = blockIdx.x * 256 + threadIdx.x;  // slice-local
  int pg = p_base + pl;
  int w = pg & 63, h = (pg >> 6) & 63, b = pg >> 12;
  float inv_c = inv_norm[pg];
  float vals[32];
#pragma unroll
  for (int j = 0; j < 32; ++j) {
    float v = 0.0f;
    if (j < 25) {
      int dc = j / 5 - 2, dr = j % 5 - 2;
      int hh = h + dr, ww = w + dc;
      if (hh >= 0 && hh < 64 && ww >= 0 && ww < 64) {
        float s = part[(size_t)(0 * 25 + j) * npix_s + pl]
                + part[(size_t)(1 * 25 + j) * npix_s + pl]
                + part[(size_t)(2 * 25 + j) * npix_s + pl]
                + part[(size_t)(3 * 25 + j) * npix_s + pl];
        v = s * inv_c * inv_norm[(b << 12) + (hh << 6) + ww];
      }
    }
    vals[j] = v;
  }
  unsigned short* xp = xb + (size_t)pl * KPAD + 1024;
#pragma unroll
  for (int g = 0; g < 4; ++g) {
    u16x8 pk;
#pragma unroll
    for (int e = 0; e < 8; ++e) pk[e] = f2bf(vals[g * 8 + e]);
    *reinterpret_cast<u16x8*>(xp + g * 8) = pk;
  }
}

// ---------------------------------------------------------------------------
// K5: GEMM out[o][p] = relu(sum_k w[o][k]*x[p][k] + bias[o])  — single bf16.
//     BM=BN=128, BK=32, 4 waves, 16x16x32 MFMA, global_load_lds staging w/
//     source-side XOR swizzle, XCD-clustered block mapping.
// ---------------------------------------------------------------------------
__device__ __forceinline__ void stage_tile(const unsigned short* __restrict__ g,
                                           unsigned short* s, int t) {
#pragma unroll
  for (int r = 0; r < 2; ++r) {
    int idx = t + r * 256;
    int row = idx >> 2;                       // tile row 0..127
    int q = (idx & 3) ^ ((row >> 1) & 3);     // swizzled 16B chunk
    const unsigned short* gp = g + (size_t)row * KPAD + q * 8;
    unsigned short* sp = s + (t >> 6) * 512 + r * 2048;  // wave-uniform base
    __builtin_amdgcn_global_load_lds((gas_t)gp, (las_t)sp, 16, 0, 0);
  }
}

__global__ __launch_bounds__(256, 2) void gemm_kernel(
    const unsigned short* __restrict__ xb, const unsigned short* __restrict__ wb,
    const float* __restrict__ bias, float* __restrict__ out,
    int p_base, int np) {
  __shared__ __align__(16) unsigned short sA[4096];
  __shared__ __align__(16) unsigned short sB[4096];
  int t = threadIdx.x;
  int lane = t & 63;
  int wid = t >> 6;
  int wm = wid >> 1, wn = wid & 1;
  int l15 = lane & 15, l4 = lane >> 4;
  int bid = blockIdx.x;
  int xcd = bid & 7;
  int j = bid >> 3;                 // per-XCD sequence 0..np-1
  int o0 = (j & 7) * 128;
  int panel = xcd * (np >> 3) + (j >> 3);
  int p0l = panel * 128;            // slice-local pixel base

  f32x4 acc[4][4];
#pragma unroll
  for (int m = 0; m < 4; ++m)
#pragma unroll
    for (int n = 0; n < 4; ++n)
#pragma unroll
      for (int i = 0; i < 4; ++i) acc[m][n][i] = 0.0f;

  const unsigned short* A = wb + (size_t)o0 * KPAD;
  const unsigned short* B = xb + (size_t)p0l * KPAD;

  for (int kt = 0; kt < KPAD / 32; ++kt) {
    int k0 = kt * 32;
    stage_tile(A + k0, sA, t);
    stage_tile(B + k0, sB, t);
    __syncthreads();

    bf16x8 bf[4];
#pragma unroll
    for (int n = 0; n < 4; ++n) {
      int rr = wn * 64 + n * 16 + l15;
      int off = rr * 32 + ((l4 ^ ((rr >> 1) & 3)) * 8);
      bf[n] = *reinterpret_cast<const bf16x8*>(&sB[off]);
    }
#pragma unroll
    for (int m = 0; m < 4; ++m) {
      int ra = wm * 64 + m * 16 + l15;
      int off = ra * 32 + ((l4 ^ ((ra >> 1) & 3)) * 8);
      bf16x8 af = *reinterpret_cast<const bf16x8*>(&sA[off]);
#pragma unroll
      for (int n = 0; n < 4; ++n)
        acc[m][n] = __builtin_amdgcn_mfma_f32_16x16x32_bf16(af, bf[n], acc[m][n], 0, 0, 0);
    }
    __syncthreads();
  }

  // epilogue: D row=o (l4*4+reg), col=p (l15); hw-contiguous coalesced stores.
#pragma unroll
  for (int m = 0; m < 4; ++m) {
    int ob = o0 + wm * 64 + m * 16 + l4 * 4;
    float b0 = bias[ob], b1 = bias[ob + 1], b2 = bias[ob + 2], b3 = bias[ob + 3];
#pragma unroll
    for (int n = 0; n < 4; ++n) {
      int pg = p_base + p0l + wn * 64 + n * 16 + l15;
      int bb = pg >> 12, hw = pg & 4095;
      float* op = out + ((size_t)bb << 22) + hw;
      op[(size_t)(ob + 0) << 12] = fmaxf(acc[m][n][0] + b0, 0.0f);
      op[(size_t)(ob + 1) << 12] = fmaxf(acc[m][n][1] + b1, 0.0f);
      op[(size_t)(ob + 2) << 12] = fmaxf(acc[m][n][2] + b2, 0.0f);
      op[(size_t)(ob + 3) << 12] = fmaxf(acc[m][n][3] + b3, 0.0f);
    }
  }
}

// ---------------------------------------------------------------------------
extern "C" void kernel_launch(void* const* d_in, const int* in_sizes, int n_in,
                              void* d_out, int out_size, void* d_ws, size_t ws_size,
                              hipStream_t stream) {
  const float* feat = (const float*)d_in[0];
  const float* cw   = (const float*)d_in[1];
  const float* cb   = (const float*)d_in[2];
  float* out = (float*)d_out;

  // NB=8 single pass: footprint 84.7 MB; round-4 fill counters proved
  // ws_size = 512 MiB. Kernel bodies identical to the twice-validated ones.
  const int NB = 8;
  const int npix_s = NB * 4096;   // 32768

  char* ws = (char*)d_ws;
  size_t SZ_XS = (size_t)npix_s * KPAD * 2;   // 69.2 MB
  size_t SZ_W  = (size_t)1024 * KPAD * 2;     //  2.16 MB
  unsigned short* xb = (unsigned short*)(ws);
  unsigned short* wb = (unsigned short*)(ws + SZ_XS);
  float* inv_norm    = (float*)(ws + SZ_XS + SZ_W);
  float* part        = (float*)(ws + SZ_XS + SZ_W + (size_t)NPIX * 4);

  prep_w<<<1024, 256, 0, stream>>>(cw, wb);
  pack_norm<<<NB * 64, 256, 0, stream>>>(feat, xb, inv_norm, 0);
  corr_part<<<NB * 64, 256, 0, stream>>>(feat, part, 0, npix_s);
  corr_reduce<<<npix_s / 256, 256, 0, stream>>>(part, inv_norm, xb, 0, npix_s);
  gemm_kernel<<<8 * NB * 32, 256, 0, stream>>>(xb, wb, cb, out, 0, NB * 32);
}

// Round 7
// 429.464 us; speedup vs baseline: 1.7863x; 1.0520x over previous
//
#include <hip/hip_runtime.h>
#include <stdint.h>

#define C_DIM 1024
#define HW    4096
#define KPAD  1056
#define KIN   1049
#define NPIX  32768   // 8*64*64
#define NCHUNK 16     // corr channel chunks (64 ch each)

typedef __bf16 bf16x8 __attribute__((ext_vector_type(8)));
typedef float  f32x4  __attribute__((ext_vector_type(4)));
typedef float  f32x2  __attribute__((ext_vector_type(2)));
typedef unsigned short u16x8 __attribute__((ext_vector_type(8)));

typedef const __attribute__((address_space(1))) void* gas_t;
typedef __attribute__((address_space(3))) void* las_t;

__device__ __forceinline__ unsigned short f2bf(float f) {
  unsigned u = __float_as_uint(f);
  unsigned r = u + 0x7FFFu + ((u >> 16) & 1u);
  return (unsigned short)(r >> 16);
}

// ---------------------------------------------------------------------------
// K1: pack conv_w [1024][1049] fp32 -> wb [1024][1056] bf16 (zero pad tail)
// ---------------------------------------------------------------------------
__global__ __launch_bounds__(256) void prep_w(const float* __restrict__ cw,
                                              unsigned short* __restrict__ wb) {
  int o = blockIdx.x;
  for (int k = threadIdx.x; k < KPAD; k += 256) {
    float v = (k < KIN) ? cw[(size_t)o * KIN + k] : 0.0f;
    wb[(size_t)o * KPAD + k] = f2bf(v);
  }
}

// ---------------------------------------------------------------------------
// K2: feature fp32 -> xb rows cols 0..1023 + inv_norm
//     One block = 64 pixels x all 1024 channels; LDS transpose.
// ---------------------------------------------------------------------------
__global__ __launch_bounds__(256) void pack_norm(const float* __restrict__ feat,
                                                 unsigned short* __restrict__ xb,
                                                 float* __restrict__ inv_norm,
                                                 int p_base) {
  __shared__ float tile[64][65];
  __shared__ float red[4][64];
  int t   = threadIdx.x;
  int p0l = blockIdx.x * 64;
  int p0g = p_base + p0l;
  int b   = p0g >> 12;
  int hw0 = p0g & 4095;
  int pl = t & 63;
  int q  = t >> 6;
  const float* fb = feat + (size_t)b * C_DIM * HW + hw0;
  float sumsq = 0.0f;
  for (int cc = 0; cc < 16; ++cc) {
#pragma unroll
    for (int i = 0; i < 16; ++i) {
      int cl = q + 4 * i;
      float v = fb[(size_t)(cc * 64 + cl) * HW + pl];
      sumsq += v * v;
      tile[cl][pl] = v;
    }
    __syncthreads();
#pragma unroll
    for (int r = 0; r < 2; ++r) {
      int id = t + r * 256;
      int pr = id >> 3;
      int c8 = id & 7;
      u16x8 hv;
#pragma unroll
      for (int e = 0; e < 8; ++e) hv[e] = f2bf(tile[c8 * 8 + e][pr]);
      size_t row = (size_t)(p0l + pr) * KPAD + cc * 64 + c8 * 8;
      *reinterpret_cast<u16x8*>(xb + row) = hv;
    }
    __syncthreads();
  }
  red[q][pl] = sumsq;
  __syncthreads();
  if (t < 64) {
    float s = red[0][t] + red[1][t] + red[2][t] + red[3][t];
    inv_norm[p0g + t] = 1.0f / fmaxf(sqrtf(s), 1e-12f);
  }
}

// ---------------------------------------------------------------------------
// K3 v2: windowed correlation partials. Block = (b, 16-row strip, 64-ch chunk),
//   4 px/thread. Stage 20x64 halo tile via global_load_lds (per-lane clamped
//   source rows); per channel: 5 rows x {b128 + 2x float2} reads, 100 FMA.
//   OOB window reads hit in-bounds garbage -> flows only into accumulators
//   that corr_reduce discards (hh/ww OOB => v=0 without reading part).
// ---------------------------------------------------------------------------
__global__ __launch_bounds__(256) void corr_part(const float* __restrict__ feat,
                                                 float* __restrict__ part) {
  __shared__ float lds4[4 + 1280 + 4];   // guard | tile[20][64] | guard
  float* tile = lds4 + 4;
  int t = threadIdx.x;
  int bid = blockIdx.x;
  int chunk = bid & 15;
  int strip = (bid >> 4) & 3;
  int b     = bid >> 6;
  int h0 = strip * 16;
  int hr = t >> 4;          // thread's row within strip (0..15)
  int w0 = (t & 15) * 4;    // thread's 4 pixels w0..w0+3
  int wid = t >> 6;
  int lane = t & 63;

  const float* fb = feat + (size_t)b * C_DIM * HW;
  // staging source offsets (per-lane clamped rows)
  int rA = t >> 4;                    // issueA: float idx t*4 -> row t>>4
  int cA = (t & 15) * 4;
  int hA = min(max(h0 - 2 + rA, 0), 63);
  int rB = 16 + wid;                  // issueB: float idx 1024+t -> row 16+wid
  int cB = lane;
  int hB = min(max(h0 - 2 + rB, 0), 63);
  const float* srcA = fb + hA * 64 + cA;
  const float* srcB = fb + hB * 64 + cB;
  float* dstA = tile + wid * 256;     // wave-uniform; HW adds lane*16
  float* dstB = tile + 1024 + wid * 64;  // wave-uniform; HW adds lane*4

  float acc[4][25];
#pragma unroll
  for (int j = 0; j < 4; ++j)
#pragma unroll
    for (int k = 0; k < 25; ++k) acc[j][k] = 0.0f;

  int c0 = chunk * 64;
  for (int ci = 0; ci < 64; ++ci) {
    size_t coff = (size_t)(c0 + ci) * HW;
    __builtin_amdgcn_global_load_lds((gas_t)(srcA + coff), (las_t)dstA, 16, 0, 0);
    __builtin_amdgcn_global_load_lds((gas_t)(srcB + coff), (las_t)dstB, 4, 0, 0);
    __syncthreads();   // drains vmcnt -> tile ready

    const float* rp2 = tile + (hr + 2) * 64 + w0;
    f32x4 ctr4 = *reinterpret_cast<const f32x4*>(rp2);
#pragma unroll
    for (int r5 = 0; r5 < 5; ++r5) {
      const float* rp = tile + (hr + r5) * 64 + w0;
      f32x2 eL = *reinterpret_cast<const f32x2*>(rp - 2);
      f32x4 cc4 = *reinterpret_cast<const f32x4*>(rp);
      f32x2 eR = *reinterpret_cast<const f32x2*>(rp + 4);
      float win[8] = {eL[0], eL[1], cc4[0], cc4[1], cc4[2], cc4[3], eR[0], eR[1]};
#pragma unroll
      for (int j = 0; j < 4; ++j)
#pragma unroll
        for (int dcv = 0; dcv < 5; ++dcv)
          acc[j][dcv * 5 + r5] += win[j + dcv] * ctr4[j];
    }
    __syncthreads();   // protect tile before next stage
  }

  int p0 = b * 4096 + (h0 + hr) * 64 + w0;
#pragma unroll
  for (int jj = 0; jj < 25; ++jj) {
    f32x4 v = {acc[0][jj], acc[1][jj], acc[2][jj], acc[3][jj]};
    *reinterpret_cast<f32x4*>(&part[(size_t)(chunk * 25 + jj) * NPIX + p0]) = v;
  }
}

// ---------------------------------------------------------------------------
// K4: reduce 16 chunks, scale by inv[p]*inv[p+d], write x cols 1024..1055
//     as 4 vectorized u16x8 stores (j>=25 zeros).
// ---------------------------------------------------------------------------
__global__ __launch_bounds__(256) void corr_reduce(const float* __restrict__ part,
                                                   const float* __restrict__ inv_norm,
                                                   unsigned short* __restrict__ xb) {
  int pl = blockIdx.x * 256 + threadIdx.x;
  int w = pl & 63, h = (pl >> 6) & 63, b = pl >> 12;
  float inv_c = inv_norm[pl];
  float vals[32];
#pragma unroll
  for (int j = 0; j < 32; ++j) {
    float v = 0.0f;
    if (j < 25) {
      int dc = j / 5 - 2, dr = j % 5 - 2;
      int hh = h + dr, ww = w + dc;
      if (hh >= 0 && hh < 64 && ww >= 0 && ww < 64) {
        float s = 0.0f;
#pragma unroll
        for (int c = 0; c < NCHUNK; ++c)
          s += part[(size_t)(c * 25 + j) * NPIX + pl];
        v = s * inv_c * inv_norm[(b << 12) + (hh << 6) + ww];
      }
    }
    vals[j] = v;
  }
  unsigned short* xp = xb + (size_t)pl * KPAD + 1024;
#pragma unroll
  for (int g = 0; g < 4; ++g) {
    u16x8 pk;
#pragma unroll
    for (int e = 0; e < 8; ++e) pk[e] = f2bf(vals[g * 8 + e]);
    *reinterpret_cast<u16x8*>(xp + g * 8) = pk;
  }
}

// ---------------------------------------------------------------------------
// K5: GEMM out[o][p] = relu(sum_k w[o][k]*x[p][k] + bias[o])  — single bf16.
//     BM=BN=128, BK=32, 4 waves, 16x16x32 MFMA, global_load_lds staging w/
//     source-side XOR swizzle, XCD-clustered block mapping. (unchanged)
// ---------------------------------------------------------------------------
__device__ __forceinline__ void stage_tile(const unsigned short* __restrict__ g,
                                           unsigned short* s, int t) {
#pragma unroll
  for (int r = 0; r < 2; ++r) {
    int idx = t + r * 256;
    int row = idx >> 2;
    int q = (idx & 3) ^ ((row >> 1) & 3);
    const unsigned short* gp = g + (size_t)row * KPAD + q * 8;
    unsigned short* sp = s + (t >> 6) * 512 + r * 2048;
    __builtin_amdgcn_global_load_lds((gas_t)gp, (las_t)sp, 16, 0, 0);
  }
}

__global__ __launch_bounds__(256, 2) void gemm_kernel(
    const unsigned short* __restrict__ xb, const unsigned short* __restrict__ wb,
    const float* __restrict__ bias, float* __restrict__ out,
    int p_base, int np) {
  __shared__ __align__(16) unsigned short sA[4096];
  __shared__ __align__(16) unsigned short sB[4096];
  int t = threadIdx.x;
  int lane = t & 63;
  int wid = t >> 6;
  int wm = wid >> 1, wn = wid & 1;
  int l15 = lane & 15, l4 = lane >> 4;
  int bid = blockIdx.x;
  int xcd = bid & 7;
  int j = bid >> 3;
  int o0 = (j & 7) * 128;
  int panel = xcd * (np >> 3) + (j >> 3);
  int p0l = panel * 128;

  f32x4 acc[4][4];
#pragma unroll
  for (int m = 0; m < 4; ++m)
#pragma unroll
    for (int n = 0; n < 4; ++n)
#pragma unroll
      for (int i = 0; i < 4; ++i) acc[m][n][i] = 0.0f;

  const unsigned short* A = wb + (size_t)o0 * KPAD;
  const unsigned short* B = xb + (size_t)p0l * KPAD;

  for (int kt = 0; kt < KPAD / 32; ++kt) {
    int k0 = kt * 32;
    stage_tile(A + k0, sA, t);
    stage_tile(B + k0, sB, t);
    __syncthreads();

    bf16x8 bf[4];
#pragma unroll
    for (int n = 0; n < 4; ++n) {
      int rr = wn * 64 + n * 16 + l15;
      int off = rr * 32 + ((l4 ^ ((rr >> 1) & 3)) * 8);
      bf[n] = *reinterpret_cast<const bf16x8*>(&sB[off]);
    }
#pragma unroll
    for (int m = 0; m < 4; ++m) {
      int ra = wm * 64 + m * 16 + l15;
      int off = ra * 32 + ((l4 ^ ((ra >> 1) & 3)) * 8);
      bf16x8 af = *reinterpret_cast<const bf16x8*>(&sA[off]);
#pragma unroll
      for (int n = 0; n < 4; ++n)
        acc[m][n] = __builtin_amdgcn_mfma_f32_16x16x32_bf16(af, bf[n], acc[m][n], 0, 0, 0);
    }
    __syncthreads();
  }

#pragma unroll
  for (int m = 0; m < 4; ++m) {
    int ob = o0 + wm * 64 + m * 16 + l4 * 4;
    float b0 = bias[ob], b1 = bias[ob + 1], b2 = bias[ob + 2], b3 = bias[ob + 3];
#pragma unroll
    for (int n = 0; n < 4; ++n) {
      int pg = p_base + p0l + wn * 64 + n * 16 + l15;
      int bb = pg >> 12, hw = pg & 4095;
      float* op = out + ((size_t)bb << 22) + hw;
      op[(size_t)(ob + 0) << 12] = fmaxf(acc[m][n][0] + b0, 0.0f);
      op[(size_t)(ob + 1) << 12] = fmaxf(acc[m][n][1] + b1, 0.0f);
      op[(size_t)(ob + 2) << 12] = fmaxf(acc[m][n][2] + b2, 0.0f);
      op[(size_t)(ob + 3) << 12] = fmaxf(acc[m][n][3] + b3, 0.0f);
    }
  }
}

// ---------------------------------------------------------------------------
extern "C" void kernel_launch(void* const* d_in, const int* in_sizes, int n_in,
                              void* d_out, int out_size, void* d_ws, size_t ws_size,
                              hipStream_t stream) {
  const float* feat = (const float*)d_in[0];
  const float* cw   = (const float*)d_in[1];
  const float* cb   = (const float*)d_in[2];
  float* out = (float*)d_out;

  // single pass: xb 69.2MB + wb 2.2MB + inv 0.13MB + part 52.4MB = 124MB < 512MiB
  char* ws = (char*)d_ws;
  size_t SZ_X = (size_t)NPIX * KPAD * 2;
  size_t SZ_W = (size_t)1024 * KPAD * 2;
  unsigned short* xb = (unsigned short*)(ws);
  unsigned short* wb = (unsigned short*)(ws + SZ_X);
  float* inv_norm    = (float*)(ws + SZ_X + SZ_W);
  float* part        = (float*)(ws + SZ_X + SZ_W + (size_t)NPIX * 4);

  prep_w<<<1024, 256, 0, stream>>>(cw, wb);
  pack_norm<<<512, 256, 0, stream>>>(feat, xb, inv_norm, 0);
  corr_part<<<512, 256, 0, stream>>>(feat, part);
  corr_reduce<<<128, 256, 0, stream>>>(part, inv_norm, xb);
  gemm_kernel<<<2048, 256, 0, stream>>>(xb, wb, cb, out, 0, 256);
}

// Round 8
// 412.772 us; speedup vs baseline: 1.8585x; 1.0404x over previous
//
#include <hip/hip_runtime.h>
#include <stdint.h>

#define C_DIM 1024
#define HW    4096
#define KPAD  1056
#define KIN   1049
#define NPIX  32768   // 8*64*64
#define NCHUNK 16     // corr channel chunks (64 ch each)

typedef __bf16 bf16x8 __attribute__((ext_vector_type(8)));
typedef float  f32x4  __attribute__((ext_vector_type(4)));
typedef float  f32x2  __attribute__((ext_vector_type(2)));
typedef unsigned short u16x8 __attribute__((ext_vector_type(8)));

typedef const __attribute__((address_space(1))) void* gas_t;
typedef __attribute__((address_space(3))) void* las_t;

__device__ __forceinline__ unsigned short f2bf(float f) {
  unsigned u = __float_as_uint(f);
  unsigned r = u + 0x7FFFu + ((u >> 16) & 1u);
  return (unsigned short)(r >> 16);
}

// ---------------------------------------------------------------------------
// K1: pack conv_w [1024][1049] fp32 -> wb [1024][1056] bf16 (zero pad tail)
// ---------------------------------------------------------------------------
__global__ __launch_bounds__(256) void prep_w(const float* __restrict__ cw,
                                              unsigned short* __restrict__ wb) {
  int o = blockIdx.x;
  for (int k = threadIdx.x; k < KPAD; k += 256) {
    float v = (k < KIN) ? cw[(size_t)o * KIN + k] : 0.0f;
    wb[(size_t)o * KPAD + k] = f2bf(v);
  }
}

// ---------------------------------------------------------------------------
// K2: feature fp32 -> xb rows cols 0..1023 + inv_norm (unchanged, validated)
// ---------------------------------------------------------------------------
__global__ __launch_bounds__(256) void pack_norm(const float* __restrict__ feat,
                                                 unsigned short* __restrict__ xb,
                                                 float* __restrict__ inv_norm,
                                                 int p_base) {
  __shared__ float tile[64][65];
  __shared__ float red[4][64];
  int t   = threadIdx.x;
  int p0l = blockIdx.x * 64;
  int p0g = p_base + p0l;
  int b   = p0g >> 12;
  int hw0 = p0g & 4095;
  int pl = t & 63;
  int q  = t >> 6;
  const float* fb = feat + (size_t)b * C_DIM * HW + hw0;
  float sumsq = 0.0f;
  for (int cc = 0; cc < 16; ++cc) {
#pragma unroll
    for (int i = 0; i < 16; ++i) {
      int cl = q + 4 * i;
      float v = fb[(size_t)(cc * 64 + cl) * HW + pl];
      sumsq += v * v;
      tile[cl][pl] = v;
    }
    __syncthreads();
#pragma unroll
    for (int r = 0; r < 2; ++r) {
      int id = t + r * 256;
      int pr = id >> 3;
      int c8 = id & 7;
      u16x8 hv;
#pragma unroll
      for (int e = 0; e < 8; ++e) hv[e] = f2bf(tile[c8 * 8 + e][pr]);
      size_t row = (size_t)(p0l + pr) * KPAD + cc * 64 + c8 * 8;
      *reinterpret_cast<u16x8*>(xb + row) = hv;
    }
    __syncthreads();
  }
  red[q][pl] = sumsq;
  __syncthreads();
  if (t < 64) {
    float s = red[0][t] + red[1][t] + red[2][t] + red[3][t];
    inv_norm[p0g + t] = 1.0f / fmaxf(sqrtf(s), 1e-12f);
  }
}

// ---------------------------------------------------------------------------
// K3 v3: corr partials, 2-phase double-buffered channel pipeline.
//   Block = (b, 16-row strip, 64-ch chunk), 4 px/thread, 2 channels/iter.
//   STAGE next 2 channels into buf^1 BEFORE computing cur; ONE barrier/iter
//   (drains next-tile vmcnt + cur-tile reads together) -> HBM latency hides
//   under the 200-FMA compute phase instead of being exposed per channel.
// ---------------------------------------------------------------------------
__global__ __launch_bounds__(256) void corr_part(const float* __restrict__ feat,
                                                 float* __restrict__ part) {
  __shared__ float lbuf[2][2][1288];   // [dbuf][ch][4 guard | 20x64 | 4 guard]
  int t = threadIdx.x;
  int bid = blockIdx.x;
  int chunk = bid & 15;
  int strip = (bid >> 4) & 3;
  int b     = bid >> 6;
  int h0 = strip * 16;
  int hr = t >> 4;          // row within strip (0..15)
  int w0 = (t & 15) * 4;    // 4 pixels w0..w0+3
  int wid = t >> 6;
  int lane = t & 63;

  const float* fb = feat + (size_t)b * C_DIM * HW;
  // staging source offsets (per-lane clamped rows, garbage-tolerant edges)
  int rA = t >> 4;
  int cA = (t & 15) * 4;
  int hA = min(max(h0 - 2 + rA, 0), 63);
  int rB = 16 + wid;
  int cB = lane;
  int hB = min(max(h0 - 2 + rB, 0), 63);
  const float* srcA = fb + hA * 64 + cA;
  const float* srcB = fb + hB * 64 + cB;
  int c0 = chunk * 64;

  float acc[4][25];
#pragma unroll
  for (int j = 0; j < 4; ++j)
#pragma unroll
    for (int k = 0; k < 25; ++k) acc[j][k] = 0.0f;

  // stage channel (c0+c) into lbuf[bsel][csel]
  auto stage = [&](int bsel, int csel, int c) {
    float* dst = &lbuf[bsel][csel][4];
    size_t coff = (size_t)(c0 + c) * HW;
    __builtin_amdgcn_global_load_lds((gas_t)(srcA + coff),
                                     (las_t)(dst + wid * 256), 16, 0, 0);
    __builtin_amdgcn_global_load_lds((gas_t)(srcB + coff),
                                     (las_t)(dst + 1024 + wid * 64), 4, 0, 0);
  };

  stage(0, 0, 0);
  stage(0, 1, 1);
  __syncthreads();

  int cur = 0;
  for (int it = 0; it < 32; ++it) {
    if (it < 31) {
      stage(cur ^ 1, 0, 2 * it + 2);
      stage(cur ^ 1, 1, 2 * it + 3);
    }
#pragma unroll
    for (int cc = 0; cc < 2; ++cc) {
      const float* tile = &lbuf[cur][cc][4];
      const float* rp2 = tile + (hr + 2) * 64 + w0;
      f32x4 ctr4 = *reinterpret_cast<const f32x4*>(rp2);
#pragma unroll
      for (int r5 = 0; r5 < 5; ++r5) {
        const float* rp = tile + (hr + r5) * 64 + w0;
        f32x2 eL = *reinterpret_cast<const f32x2*>(rp - 2);
        f32x4 cc4 = *reinterpret_cast<const f32x4*>(rp);
        f32x2 eR = *reinterpret_cast<const f32x2*>(rp + 4);
        float win[8] = {eL[0], eL[1], cc4[0], cc4[1], cc4[2], cc4[3], eR[0], eR[1]};
#pragma unroll
        for (int j = 0; j < 4; ++j)
#pragma unroll
          for (int dcv = 0; dcv < 5; ++dcv)
            acc[j][dcv * 5 + r5] += win[j + dcv] * ctr4[j];
      }
    }
    __syncthreads();   // drains: my reads of cur done + next tile landed
    cur ^= 1;
  }

  int p0 = b * 4096 + (h0 + hr) * 64 + w0;
#pragma unroll
  for (int jj = 0; jj < 25; ++jj) {
    f32x4 v = {acc[0][jj], acc[1][jj], acc[2][jj], acc[3][jj]};
    *reinterpret_cast<f32x4*>(&part[(size_t)(chunk * 25 + jj) * NPIX + p0]) = v;
  }
}

// ---------------------------------------------------------------------------
// K4: reduce 16 chunks, scale by inv[p]*inv[p+d], write x cols 1024..1055
// ---------------------------------------------------------------------------
__global__ __launch_bounds__(256) void corr_reduce(const float* __restrict__ part,
                                                   const float* __restrict__ inv_norm,
                                                   unsigned short* __restrict__ xb) {
  int pl = blockIdx.x * 256 + threadIdx.x;
  int w = pl & 63, h = (pl >> 6) & 63, b = pl >> 12;
  float inv_c = inv_norm[pl];
  float vals[32];
#pragma unroll
  for (int j = 0; j < 32; ++j) {
    float v = 0.0f;
    if (j < 25) {
      int dc = j / 5 - 2, dr = j % 5 - 2;
      int hh = h + dr, ww = w + dc;
      if (hh >= 0 && hh < 64 && ww >= 0 && ww < 64) {
        float s = 0.0f;
#pragma unroll
        for (int c = 0; c < NCHUNK; ++c)
          s += part[(size_t)(c * 25 + j) * NPIX + pl];
        v = s * inv_c * inv_norm[(b << 12) + (hh << 6) + ww];
      }
    }
    vals[j] = v;
  }
  unsigned short* xp = xb + (size_t)pl * KPAD + 1024;
#pragma unroll
  for (int g = 0; g < 4; ++g) {
    u16x8 pk;
#pragma unroll
    for (int e = 0; e < 8; ++e) pk[e] = f2bf(vals[g * 8 + e]);
    *reinterpret_cast<u16x8*>(xp + g * 8) = pk;
  }
}

// ---------------------------------------------------------------------------
// K5: GEMM, 2-phase double-buffered K-loop (T3 minimum pattern).
//     Stage tile kt+1 into buf^1 BEFORE computing tile kt; ONE barrier/step.
//     BM=BN=128, BK=32, 4 waves, 16x16x32 MFMA, source-side XOR swizzle,
//     XCD-clustered block mapping.
// ---------------------------------------------------------------------------
__device__ __forceinline__ void stage_tile(const unsigned short* __restrict__ g,
                                           unsigned short* s, int t) {
#pragma unroll
  for (int r = 0; r < 2; ++r) {
    int idx = t + r * 256;
    int row = idx >> 2;
    int q = (idx & 3) ^ ((row >> 1) & 3);
    const unsigned short* gp = g + (size_t)row * KPAD + q * 8;
    unsigned short* sp = s + (t >> 6) * 512 + r * 2048;
    __builtin_amdgcn_global_load_lds((gas_t)gp, (las_t)sp, 16, 0, 0);
  }
}

__global__ __launch_bounds__(256, 2) void gemm_kernel(
    const unsigned short* __restrict__ xb, const unsigned short* __restrict__ wb,
    const float* __restrict__ bias, float* __restrict__ out,
    int p_base, int np) {
  __shared__ __align__(16) unsigned short sA[2][4096];
  __shared__ __align__(16) unsigned short sB[2][4096];
  int t = threadIdx.x;
  int lane = t & 63;
  int wid = t >> 6;
  int wm = wid >> 1, wn = wid & 1;
  int l15 = lane & 15, l4 = lane >> 4;
  int bid = blockIdx.x;
  int xcd = bid & 7;
  int j = bid >> 3;
  int o0 = (j & 7) * 128;
  int panel = xcd * (np >> 3) + (j >> 3);
  int p0l = panel * 128;

  f32x4 acc[4][4];
#pragma unroll
  for (int m = 0; m < 4; ++m)
#pragma unroll
    for (int n = 0; n < 4; ++n)
#pragma unroll
      for (int i = 0; i < 4; ++i) acc[m][n][i] = 0.0f;

  const unsigned short* A = wb + (size_t)o0 * KPAD;
  const unsigned short* B = xb + (size_t)p0l * KPAD;

  stage_tile(A, sA[0], t);
  stage_tile(B, sB[0], t);
  __syncthreads();

  int cur = 0;
  const int NKT = KPAD / 32;   // 33
  for (int kt = 0; kt < NKT; ++kt) {
    if (kt + 1 < NKT) {
      stage_tile(A + (kt + 1) * 32, sA[cur ^ 1], t);
      stage_tile(B + (kt + 1) * 32, sB[cur ^ 1], t);
    }
    bf16x8 bf[4];
#pragma unroll
    for (int n = 0; n < 4; ++n) {
      int rr = wn * 64 + n * 16 + l15;
      int off = rr * 32 + ((l4 ^ ((rr >> 1) & 3)) * 8);
      bf[n] = *reinterpret_cast<const bf16x8*>(&sB[cur][off]);
    }
#pragma unroll
    for (int m = 0; m < 4; ++m) {
      int ra = wm * 64 + m * 16 + l15;
      int off = ra * 32 + ((l4 ^ ((ra >> 1) & 3)) * 8);
      bf16x8 af = *reinterpret_cast<const bf16x8*>(&sA[cur][off]);
#pragma unroll
      for (int n = 0; n < 4; ++n)
        acc[m][n] = __builtin_amdgcn_mfma_f32_16x16x32_bf16(af, bf[n], acc[m][n], 0, 0, 0);
    }
    __syncthreads();   // my reads of cur done + next tile landed
    cur ^= 1;
  }

#pragma unroll
  for (int m = 0; m < 4; ++m) {
    int ob = o0 + wm * 64 + m * 16 + l4 * 4;
    float b0 = bias[ob], b1 = bias[ob + 1], b2 = bias[ob + 2], b3 = bias[ob + 3];
#pragma unroll
    for (int n = 0; n < 4; ++n) {
      int pg = p_base + p0l + wn * 64 + n * 16 + l15;
      int bb = pg >> 12, hw = pg & 4095;
      float* op = out + ((size_t)bb << 22) + hw;
      op[(size_t)(ob + 0) << 12] = fmaxf(acc[m][n][0] + b0, 0.0f);
      op[(size_t)(ob + 1) << 12] = fmaxf(acc[m][n][1] + b1, 0.0f);
      op[(size_t)(ob + 2) << 12] = fmaxf(acc[m][n][2] + b2, 0.0f);
      op[(size_t)(ob + 3) << 12] = fmaxf(acc[m][n][3] + b3, 0.0f);
    }
  }
}

// ---------------------------------------------------------------------------
extern "C" void kernel_launch(void* const* d_in, const int* in_sizes, int n_in,
                              void* d_out, int out_size, void* d_ws, size_t ws_size,
                              hipStream_t stream) {
  const float* feat = (const float*)d_in[0];
  const float* cw   = (const float*)d_in[1];
  const float* cb   = (const float*)d_in[2];
  float* out = (float*)d_out;

  // single pass: xb 69.2MB + wb 2.2MB + inv 0.13MB + part 52.4MB = 124MB < 512MiB
  char* ws = (char*)d_ws;
  size_t SZ_X = (size_t)NPIX * KPAD * 2;
  size_t SZ_W = (size_t)1024 * KPAD * 2;
  unsigned short* xb = (unsigned short*)(ws);
  unsigned short* wb = (unsigned short*)(ws + SZ_X);
  float* inv_norm    = (float*)(ws + SZ_X + SZ_W);
  float* part        = (float*)(ws + SZ_X + SZ_W + (size_t)NPIX * 4);

  prep_w<<<1024, 256, 0, stream>>>(cw, wb);
  pack_norm<<<512, 256, 0, stream>>>(feat, xb, inv_norm, 0);
  corr_part<<<512, 256, 0, stream>>>(feat, part);
  corr_reduce<<<128, 256, 0, stream>>>(part, inv_norm, xb);
  gemm_kernel<<<2048, 256, 0, stream>>>(xb, wb, cb, out, 0, 256);
}